// Round 2
// baseline (439.332 us; speedup 1.0000x reference)
//
#include <hip/hip_runtime.h>
#include <hip/hip_bf16.h>

#define S   4096
#define DM  1024
#define DK  128
#define PR_ROWS 64
#define PR_BK   32

typedef __attribute__((ext_vector_type(8))) short short8;
typedef __attribute__((ext_vector_type(4))) float f32x4;

static __device__ __forceinline__ unsigned short f2bf(float f) {
    unsigned u = __builtin_bit_cast(unsigned, f);
    unsigned r = (u + 0x7FFFu + ((u >> 16) & 1u)) >> 16;
    return (unsigned short)r;
}

// ---------------- Projection: P = X[4096x1024] @ W[1024x128] + b, bf16 out ----
// blockIdx.y selects which projection (0=q,1=k,2=v). For v, output is stored
// pre-fragmented: vpF[(row>>5)*DK*32 + col*32 + (row&31)] so attention PV
// B-frags are contiguous 16B loads.
__global__ __launch_bounds__(256) void proj_kernel(
    const float* __restrict__ q, const float* __restrict__ k, const float* __restrict__ v,
    const float* __restrict__ Wq, const float* __restrict__ bq,
    const float* __restrict__ Wk, const float* __restrict__ bk,
    const float* __restrict__ Wv, const float* __restrict__ bv,
    unsigned short* __restrict__ qp, unsigned short* __restrict__ kp,
    unsigned short* __restrict__ vpF)
{
    const int pid = blockIdx.y;
    const float* X    = pid == 0 ? q  : (pid == 1 ? k  : v);
    const float* W    = pid == 0 ? Wq : (pid == 1 ? Wk : Wv);
    const float* bias = pid == 0 ? bq : (pid == 1 ? bk : bv);
    unsigned short* out = pid == 0 ? qp : (pid == 1 ? kp : vpF);

    const int row0 = blockIdx.x * PR_ROWS;
    const int tid  = threadIdx.x;
    const int lane = tid & 63;
    const int wave = tid >> 6;
    const int lw = lane & 15, lg = lane >> 4;

    __shared__ unsigned short Xs[PR_ROWS][PR_BK];  // 64x32 bf16
    __shared__ unsigned short Wt[DK][PR_BK];       // W^T tile: 128x32 bf16

    f32x4 acc[8];
    #pragma unroll
    for (int i = 0; i < 8; i++) acc[i] = f32x4{0.f, 0.f, 0.f, 0.f};

    for (int k0 = 0; k0 < DM; k0 += PR_BK) {
        // stage X tile (cast f32->bf16): 64 rows x 32 k
        {
            int r = tid >> 2;            // 4 threads per row
            int c = (tid & 3) * 8;
            const float* src = X + (size_t)(row0 + r) * DM + k0 + c;
            float4 a = *reinterpret_cast<const float4*>(src);
            float4 b = *reinterpret_cast<const float4*>(src + 4);
            short8 xb;
            xb[0] = (short)f2bf(a.x); xb[1] = (short)f2bf(a.y);
            xb[2] = (short)f2bf(a.z); xb[3] = (short)f2bf(a.w);
            xb[4] = (short)f2bf(b.x); xb[5] = (short)f2bf(b.y);
            xb[6] = (short)f2bf(b.z); xb[7] = (short)f2bf(b.w);
            *reinterpret_cast<short8*>(&Xs[r][c]) = xb;
        }
        // stage W tile transposed: 32 k x 128 cols -> Wt[col][k]
        {
            int r  = tid >> 3;           // 8 threads per row
            int c0 = (tid & 7) * 16;
            const float* src = W + (size_t)(k0 + r) * DK + c0;
            #pragma unroll
            for (int j = 0; j < 16; j += 4) {
                float4 w = *reinterpret_cast<const float4*>(src + j);
                Wt[c0 + j + 0][r] = f2bf(w.x);
                Wt[c0 + j + 1][r] = f2bf(w.y);
                Wt[c0 + j + 2][r] = f2bf(w.z);
                Wt[c0 + j + 3][r] = f2bf(w.w);
            }
        }
        __syncthreads();
        short8 af = *reinterpret_cast<const short8*>(&Xs[wave * 16 + lw][lg * 8]);
        #pragma unroll
        for (int n = 0; n < 8; n++) {
            short8 bf = *reinterpret_cast<const short8*>(&Wt[n * 16 + lw][lg * 8]);
            acc[n] = __builtin_amdgcn_mfma_f32_16x16x32_bf16(af, bf, acc[n], 0, 0, 0);
        }
        __syncthreads();
    }

    // epilogue: bias add, cast, store
    const int qrow = row0 + wave * 16 + lg * 4;
    if (pid != 2) {
        #pragma unroll
        for (int n = 0; n < 8; n++) {
            int col = n * 16 + lw;
            float bb = bias[col];
            #pragma unroll
            for (int r = 0; r < 4; r++)
                out[(size_t)(qrow + r) * DK + col] = f2bf(acc[n][r] + bb);
        }
    } else {
        #pragma unroll
        for (int n = 0; n < 8; n++) {
            int col = n * 16 + lw;
            float bb = bias[col];
            #pragma unroll
            for (int r = 0; r < 4; r++) {
                int row = qrow + r;
                out[(size_t)(row >> 5) * DK * 32 + (size_t)col * 32 + (row & 31)] =
                    f2bf(acc[n][r] + bb);
            }
        }
    }
}

// ---------------- Flash attention (causal), 1 wave = 16 query rows ------------
// Block has 2 independent waves: wave0 -> q-tile b, wave1 -> q-tile 255-b
// (balances the causal triangle). No cross-wave sync (divergent trip counts!).
__global__ __launch_bounds__(128) void attn_kernel(
    const unsigned short* __restrict__ qp,
    const unsigned short* __restrict__ kp,
    const unsigned short* __restrict__ vpF,
    float* __restrict__ out)
{
    const int lane = threadIdx.x & 63;
    const int wid  = threadIdx.x >> 6;
    const int tile = wid ? (S / 16 - 1 - (int)blockIdx.x) : (int)blockIdx.x;
    const int q0 = tile * 16;
    const int lw = lane & 15, lg = lane >> 4;

    __shared__ unsigned short Pl[2][16][32];   // per-wave P transpose buffer

    // Q fragments for 16 rows x 128 d (A-operand), kept in registers
    short8 qf[4];
    {
        const unsigned short* qb = qp + (size_t)(q0 + lw) * DK + lg * 8;
        #pragma unroll
        for (int t = 0; t < 4; t++)
            qf[t] = *reinterpret_cast<const short8*>(qb + t * 32);
    }

    f32x4 oacc[8];
    #pragma unroll
    for (int i = 0; i < 8; i++) oacc[i] = f32x4{0.f, 0.f, 0.f, 0.f};
    float m[4]    = {-1e30f, -1e30f, -1e30f, -1e30f};
    float lsum[4] = {0.f, 0.f, 0.f, 0.f};

    const float scale = 0.08838834764831843f;  // 1/sqrt(128)
    const int nt = (q0 + 47) >> 5;             // key tiles of 32 covering diag

    for (int t = 0; t < nt; ++t) {
        const int k0 = t * 32;
        // ---- QK^T: scores[16q][32k] via 2 col-tiles x 4 K-chunks ----
        f32x4 sc0 = f32x4{0.f, 0.f, 0.f, 0.f};
        f32x4 sc1 = f32x4{0.f, 0.f, 0.f, 0.f};
        {
            const unsigned short* kb0 = kp + (size_t)(k0 + lw) * DK + lg * 8;
            const unsigned short* kb1 = kb0 + 16 * DK;
            #pragma unroll
            for (int tt = 0; tt < 4; tt++) {
                short8 b0 = *reinterpret_cast<const short8*>(kb0 + tt * 32);
                short8 b1 = *reinterpret_cast<const short8*>(kb1 + tt * 32);
                sc0 = __builtin_amdgcn_mfma_f32_16x16x32_bf16(qf[tt], b0, sc0, 0, 0, 0);
                sc1 = __builtin_amdgcn_mfma_f32_16x16x32_bf16(qf[tt], b1, sc1, 0, 0, 0);
            }
        }
        // ---- online softmax (f32) ----
        float mx[4];
        #pragma unroll
        for (int r = 0; r < 4; r++) {
            int qg = q0 + lg * 4 + r;
            float s0 = sc0[r] * scale; if (k0 + lw > qg)      s0 = -1e30f;
            float s1 = sc1[r] * scale; if (k0 + 16 + lw > qg) s1 = -1e30f;
            sc0[r] = s0; sc1[r] = s1;
            mx[r] = fmaxf(s0, s1);
        }
        #pragma unroll
        for (int off = 1; off < 16; off <<= 1) {
            #pragma unroll
            for (int r = 0; r < 4; r++)
                mx[r] = fmaxf(mx[r], __shfl_xor(mx[r], off));
        }
        float corr[4], rs[4];
        #pragma unroll
        for (int r = 0; r < 4; r++) {
            float mn = fmaxf(m[r], mx[r]);
            corr[r] = __expf(m[r] - mn);
            m[r] = mn;
            float p0 = __expf(sc0[r] - mn);
            float p1 = __expf(sc1[r] - mn);
            rs[r] = p0 + p1;
            Pl[wid][lg * 4 + r][lw]      = f2bf(p0);
            Pl[wid][lg * 4 + r][16 + lw] = f2bf(p1);
        }
        #pragma unroll
        for (int off = 1; off < 16; off <<= 1) {
            #pragma unroll
            for (int r = 0; r < 4; r++)
                rs[r] += __shfl_xor(rs[r], off);
        }
        #pragma unroll
        for (int r = 0; r < 4; r++) lsum[r] = lsum[r] * corr[r] + rs[r];
        #pragma unroll
        for (int f = 0; f < 8; f++) {
            oacc[f][0] *= corr[0]; oacc[f][1] *= corr[1];
            oacc[f][2] *= corr[2]; oacc[f][3] *= corr[3];
        }
        // wave-local LDS fence: P writes -> P reads (no cross-wave use)
        asm volatile("s_waitcnt lgkmcnt(0)" ::: "memory");
        // ---- PV: oacc += P[16x32] @ V[32x128] ----
        short8 pa = *reinterpret_cast<const short8*>(&Pl[wid][lw][lg * 8]);
        const unsigned short* vb = vpF + (size_t)(k0 >> 5) * DK * 32 + lg * 8;
        #pragma unroll
        for (int f = 0; f < 8; f++) {
            short8 bf = *reinterpret_cast<const short8*>(vb + (size_t)(f * 16 + lw) * 32);
            oacc[f] = __builtin_amdgcn_mfma_f32_16x16x32_bf16(pa, bf, oacc[f], 0, 0, 0);
        }
    }
    // ---- epilogue: normalize, f32 store ----
    #pragma unroll
    for (int f = 0; f < 8; f++) {
        int col = f * 16 + lw;
        #pragma unroll
        for (int r = 0; r < 4; r++)
            out[(size_t)(q0 + lg * 4 + r) * DK + col] = oacc[f][r] / lsum[r];
    }
}

extern "C" void kernel_launch(void* const* d_in, const int* in_sizes, int n_in,
                              void* d_out, int out_size, void* d_ws, size_t ws_size,
                              hipStream_t stream) {
    const float* q  = (const float*)d_in[0];
    const float* k  = (const float*)d_in[1];
    const float* v  = (const float*)d_in[2];
    const float* Wq = (const float*)d_in[3];
    const float* bq = (const float*)d_in[4];
    const float* bk = (const float*)d_in[6];
    const float* Wk = (const float*)d_in[5];
    const float* Wv = (const float*)d_in[7];
    const float* bv = (const float*)d_in[8];

    unsigned short* qp  = (unsigned short*)d_ws;
    unsigned short* kp  = qp + (size_t)S * DK;
    unsigned short* vpF = kp + (size_t)S * DK;

    dim3 gp(S / PR_ROWS, 3);
    proj_kernel<<<gp, 256, 0, stream>>>(q, k, v, Wq, bq, Wk, bk, Wv, bv, qp, kp, vpF);
    attn_kernel<<<S / 32, 128, 0, stream>>>(qp, kp, vpF, (float*)d_out);
}

// Round 4
// 174.563 us; speedup vs baseline: 2.5168x; 2.5168x over previous
//
#include <hip/hip_runtime.h>
#include <hip/hip_bf16.h>

#define S   4096
#define DM  1024
#define DK  128

typedef __attribute__((ext_vector_type(8))) short short8;
typedef __attribute__((ext_vector_type(4))) float f32x4;

static __device__ __forceinline__ unsigned short f2bf(float f) {
    unsigned u = __builtin_bit_cast(unsigned, f);
    unsigned r = (u + 0x7FFFu + ((u >> 16) & 1u)) >> 16;
    return (unsigned short)r;
}

// ---------- W transpose: WtB[pid][col][k] = bf16(W[k][col]) ------------------
__global__ __launch_bounds__(256) void wtrans_kernel(
    const float* __restrict__ Wq, const float* __restrict__ Wk,
    const float* __restrict__ Wv, unsigned short* __restrict__ WtB)
{
    const int pid = blockIdx.z;
    const float* W = pid == 0 ? Wq : (pid == 1 ? Wk : Wv);
    unsigned short* T = WtB + (size_t)pid * DK * DM;
    const int k0 = blockIdx.x * 32, c0 = blockIdx.y * 32;
    __shared__ unsigned short tile[32][33];
    const int x = threadIdx.x & 31, y = threadIdx.x >> 5;   // 32 x 8
    #pragma unroll
    for (int i = 0; i < 32; i += 8)
        tile[y + i][x] = f2bf(W[(size_t)(k0 + y + i) * DK + c0 + x]);
    __syncthreads();
    #pragma unroll
    for (int i = 0; i < 32; i += 8)
        T[(size_t)(c0 + y + i) * DM + k0 + x] = tile[x][y + i];
}

// ---------- Projection: P = X @ W + b, bf16 out ------------------------------
// 32-row blocks, 4 waves: wave = rows (w>>1)*16, cols (w&1)*64. B-frags read
// directly from pre-transposed WtB (L2-resident, contiguous 16B per lane).
// X tile staged in LDS with XOR swizzle (16B granules) to kill the stride-128B
// bank conflict on ds_read_b128.
#define PBK 64
__global__ __launch_bounds__(256) void proj_kernel(
    const float* __restrict__ q, const float* __restrict__ k, const float* __restrict__ v,
    const float* __restrict__ bq, const float* __restrict__ bk, const float* __restrict__ bv,
    const unsigned short* __restrict__ WtB,
    unsigned short* __restrict__ qp, unsigned short* __restrict__ kp,
    unsigned short* __restrict__ vpF)
{
    const int pid = blockIdx.y;
    const float* X    = pid == 0 ? q  : (pid == 1 ? k  : v);
    const float* bias = pid == 0 ? bq : (pid == 1 ? bk : bv);
    unsigned short* out = pid == 0 ? qp : (pid == 1 ? kp : vpF);
    const unsigned short* Wt = WtB + (size_t)pid * DK * DM;

    const int rows0 = blockIdx.x * 32;
    const int tid  = threadIdx.x;
    const int lane = tid & 63;
    const int wave = tid >> 6;
    const int lw = lane & 15, lg = lane >> 4;
    const int wrow = (wave >> 1) * 16;      // 0 or 16
    const int wcol = (wave & 1) * 64;       // 0 or 64

    __shared__ unsigned short Xs[32][PBK];  // 4 KB, XOR-swizzled 16B granules

    f32x4 acc[4];
    #pragma unroll
    for (int i = 0; i < 4; i++) acc[i] = f32x4{0.f, 0.f, 0.f, 0.f};

    const int srow = tid >> 3;              // staging row (32 rows x 8 thr)
    const int sg   = tid & 7;               // staging granule
    const int sgs  = sg ^ (srow & 7);       // swizzled granule

    for (int k0 = 0; k0 < DM; k0 += PBK) {
        const float* src = X + (size_t)(rows0 + srow) * DM + k0 + sg * 8;
        float4 a = *reinterpret_cast<const float4*>(src);
        float4 b = *reinterpret_cast<const float4*>(src + 4);
        short8 xb;
        xb[0] = (short)f2bf(a.x); xb[1] = (short)f2bf(a.y);
        xb[2] = (short)f2bf(a.z); xb[3] = (short)f2bf(a.w);
        xb[4] = (short)f2bf(b.x); xb[5] = (short)f2bf(b.y);
        xb[6] = (short)f2bf(b.z); xb[7] = (short)f2bf(b.w);
        *reinterpret_cast<short8*>(&Xs[srow][sgs * 8]) = xb;
        __syncthreads();
        #pragma unroll
        for (int kk = 0; kk < 2; kk++) {
            const int g = (kk * 4 + lg) ^ (lw & 7);
            short8 af = *reinterpret_cast<const short8*>(&Xs[wrow + lw][g * 8]);
            #pragma unroll
            for (int f = 0; f < 4; f++) {
                const unsigned short* wp =
                    Wt + (size_t)(wcol + f * 16 + lw) * DM + k0 + kk * 32 + lg * 8;
                short8 bf = *reinterpret_cast<const short8*>(wp);
                acc[f] = __builtin_amdgcn_mfma_f32_16x16x32_bf16(af, bf, acc[f], 0, 0, 0);
            }
        }
        __syncthreads();
    }

    const int orow = rows0 + wrow + lg * 4;
    if (pid != 2) {
        #pragma unroll
        for (int f = 0; f < 4; f++) {
            int col = wcol + f * 16 + lw;
            float bb = bias[col];
            #pragma unroll
            for (int r = 0; r < 4; r++)
                out[(size_t)(orow + r) * DK + col] = f2bf(acc[f][r] + bb);
        }
    } else {
        #pragma unroll
        for (int f = 0; f < 4; f++) {
            int col = wcol + f * 16 + lw;
            float bb = bias[col];
            #pragma unroll
            for (int r = 0; r < 4; r++) {
                int row = orow + r;
                out[(size_t)(row >> 5) * DK * 32 + (size_t)col * 32 + (row & 31)] =
                    f2bf(acc[f][r] + bb);
            }
        }
    }
}

// ---------- Flash attention (causal), split-K: 8 waves per 16-row q-tile -----
// Wave w handles k-tiles t == w (mod 8) with private online-softmax state;
// partials combined in LDS via LSE weighting.
__global__ __launch_bounds__(512) void attn_kernel(
    const unsigned short* __restrict__ qp,
    const unsigned short* __restrict__ kp,
    const unsigned short* __restrict__ vpF,
    float* __restrict__ out)
{
    const int tid  = threadIdx.x;
    const int lane = tid & 63;
    const int wid  = tid >> 6;              // 0..7
    const int q0   = blockIdx.x * 16;
    const int lw = lane & 15, lg = lane >> 4;

    __shared__ unsigned short Pl[8][16][32];   // per-wave P transpose
    __shared__ float Ols[8][16][132];          // padded partial O
    __shared__ float mls[8][16], lls[8][16];
    __shared__ float wgt[8][16], invd[16];

    short8 qf[4];
    {
        const unsigned short* qb = qp + (size_t)(q0 + lw) * DK + lg * 8;
        #pragma unroll
        for (int t = 0; t < 4; t++)
            qf[t] = *reinterpret_cast<const short8*>(qb + t * 32);
    }

    f32x4 oacc[8];
    #pragma unroll
    for (int i = 0; i < 8; i++) oacc[i] = f32x4{0.f, 0.f, 0.f, 0.f};
    float m[4]    = {-1e30f, -1e30f, -1e30f, -1e30f};
    float lsum[4] = {0.f, 0.f, 0.f, 0.f};

    const float scale = 0.08838834764831843f;  // 1/sqrt(128)
    const int nt = (q0 + 47) >> 5;

    for (int t = wid; t < nt; t += 8) {
        const int k0 = t * 32;
        f32x4 sc0 = f32x4{0.f, 0.f, 0.f, 0.f};
        f32x4 sc1 = f32x4{0.f, 0.f, 0.f, 0.f};
        {
            const unsigned short* kb0 = kp + (size_t)(k0 + lw) * DK + lg * 8;
            const unsigned short* kb1 = kb0 + 16 * DK;
            #pragma unroll
            for (int tt = 0; tt < 4; tt++) {
                short8 b0 = *reinterpret_cast<const short8*>(kb0 + tt * 32);
                short8 b1 = *reinterpret_cast<const short8*>(kb1 + tt * 32);
                sc0 = __builtin_amdgcn_mfma_f32_16x16x32_bf16(qf[tt], b0, sc0, 0, 0, 0);
                sc1 = __builtin_amdgcn_mfma_f32_16x16x32_bf16(qf[tt], b1, sc1, 0, 0, 0);
            }
        }
        float mx[4];
        #pragma unroll
        for (int r = 0; r < 4; r++) {
            int qg = q0 + lg * 4 + r;
            float s0 = sc0[r] * scale; if (k0 + lw > qg)      s0 = -1e30f;
            float s1 = sc1[r] * scale; if (k0 + 16 + lw > qg) s1 = -1e30f;
            sc0[r] = s0; sc1[r] = s1;
            mx[r] = fmaxf(s0, s1);
        }
        #pragma unroll
        for (int off = 1; off < 16; off <<= 1) {
            #pragma unroll
            for (int r = 0; r < 4; r++)
                mx[r] = fmaxf(mx[r], __shfl_xor(mx[r], off));
        }
        float corr[4], rs[4];
        #pragma unroll
        for (int r = 0; r < 4; r++) {
            float mn = fmaxf(m[r], mx[r]);
            corr[r] = __expf(m[r] - mn);
            m[r] = mn;
            float p0 = __expf(sc0[r] - mn);
            float p1 = __expf(sc1[r] - mn);
            rs[r] = p0 + p1;
            Pl[wid][lg * 4 + r][lw]      = f2bf(p0);
            Pl[wid][lg * 4 + r][16 + lw] = f2bf(p1);
        }
        #pragma unroll
        for (int off = 1; off < 16; off <<= 1) {
            #pragma unroll
            for (int r = 0; r < 4; r++)
                rs[r] += __shfl_xor(rs[r], off);
        }
        #pragma unroll
        for (int r = 0; r < 4; r++) lsum[r] = lsum[r] * corr[r] + rs[r];
        #pragma unroll
        for (int f = 0; f < 8; f++) {
            oacc[f][0] *= corr[0]; oacc[f][1] *= corr[1];
            oacc[f][2] *= corr[2]; oacc[f][3] *= corr[3];
        }
        asm volatile("s_waitcnt lgkmcnt(0)" ::: "memory");
        short8 pa = *reinterpret_cast<const short8*>(&Pl[wid][lw][lg * 8]);
        const unsigned short* vb = vpF + (size_t)(k0 >> 5) * DK * 32 + lg * 8;
        #pragma unroll
        for (int f = 0; f < 8; f++) {
            short8 bf = *reinterpret_cast<const short8*>(vb + (size_t)(f * 16 + lw) * 32);
            oacc[f] = __builtin_amdgcn_mfma_f32_16x16x32_bf16(pa, bf, oacc[f], 0, 0, 0);
        }
    }

    // ---- write partials ----
    #pragma unroll
    for (int f = 0; f < 8; f++) {
        int col = f * 16 + lw;
        #pragma unroll
        for (int r = 0; r < 4; r++)
            Ols[wid][lg * 4 + r][col] = oacc[f][r];
    }
    if (lw == 0) {
        #pragma unroll
        for (int r = 0; r < 4; r++) {
            mls[wid][lg * 4 + r] = m[r];
            lls[wid][lg * 4 + r] = lsum[r];
        }
    }
    __syncthreads();

    // ---- per-row combine weights ----
    if (tid < 16) {
        float M = mls[0][tid];
        #pragma unroll
        for (int w2 = 1; w2 < 8; w2++) M = fmaxf(M, mls[w2][tid]);
        float d = 0.f;
        #pragma unroll
        for (int w2 = 0; w2 < 8; w2++) {
            float g = __expf(mls[w2][tid] - M);
            wgt[w2][tid] = g;
            d += g * lls[w2][tid];
        }
        invd[tid] = 1.0f / d;
    }
    __syncthreads();

    // ---- weighted combine, coalesced store ----
    #pragma unroll
    for (int j = 0; j < 4; j++) {
        int e = tid + 512 * j;
        int r = e >> 7, c = e & 127;
        float num = 0.f;
        #pragma unroll
        for (int w2 = 0; w2 < 8; w2++) num += wgt[w2][r] * Ols[w2][r][c];
        out[(size_t)(q0 + r) * DK + c] = num * invd[r];
    }
}

extern "C" void kernel_launch(void* const* d_in, const int* in_sizes, int n_in,
                              void* d_out, int out_size, void* d_ws, size_t ws_size,
                              hipStream_t stream) {
    const float* q  = (const float*)d_in[0];
    const float* k  = (const float*)d_in[1];
    const float* v  = (const float*)d_in[2];
    const float* Wq = (const float*)d_in[3];
    const float* bq = (const float*)d_in[4];
    const float* Wk = (const float*)d_in[5];
    const float* bk = (const float*)d_in[6];
    const float* Wv = (const float*)d_in[7];
    const float* bv = (const float*)d_in[8];

    unsigned short* qp  = (unsigned short*)d_ws;
    unsigned short* kp  = qp + (size_t)S * DK;
    unsigned short* vpF = kp + (size_t)S * DK;
    unsigned short* WtB = vpF + (size_t)S * DK;   // [3][128][1024] bf16

    dim3 gt(DM / 32, DK / 32, 3);
    wtrans_kernel<<<gt, 256, 0, stream>>>(Wq, Wk, Wv, WtB);

    dim3 gp(S / 32, 3);
    proj_kernel<<<gp, 256, 0, stream>>>(q, k, v, bq, bk, bv, WtB, qp, kp, vpF);

    attn_kernel<<<S / 16, 512, 0, stream>>>(qp, kp, vpF, (float*)d_out);
}